// Round 6
// baseline (26.871 us; speedup 1.0000x reference)
//
#include <hip/hip_runtime.h>

#define B_DIM 4096
#define L_DIM 512
#define NT 1000
#define OD 8
#define TOTAL (B_DIM * L_DIM)   // 2,097,152
#define CHUNK 1024               // elements per block (4 waves x 2 rounds x 128)
#define NBLK (TOTAL / CHUNK)     // 2048 -> 8 blocks/CU, 32 waves/CU

typedef float float4n __attribute__((ext_vector_type(4)));

// Fused table: unit u = 2*idx + half (16 B each), XOR-swizzled us = u^((u>>3)&7)
// into 2048 units = 32 KB — exactly one L1. Gathers read it directly from
// global memory (L1-resident); no LDS anywhere in the main kernel.
__device__ __forceinline__ int swz(int u) { return u ^ ((u >> 3) & 7); }

__global__ __launch_bounds__(256) void build_table(
    const float* __restrict__ W,     // (OD, NT)
    const float* __restrict__ bias,  // (OD,)
    float* __restrict__ wt_g)        // 2048*4 floats, swizzled layout
{
    const int k = blockIdx.x * 256 + threadIdx.x;   // 0..8191
    if (k < NT * OD) {
        const int r = k >> 3;   // time bucket
        const int j = k & 7;    // out dim
        const float val = W[j * NT + r] + bias[j];
        const int u = 2 * r + (j >> 2);
        wt_g[swz(u) * 4 + (j & 3)] = val;
    }
}

__global__ __launch_bounds__(256, 8) void ste_kernel(
    const float* __restrict__ timestamp,   // (B, L+1)
    const float* __restrict__ wt_g,        // swizzled fused table (32 KB)
    float* __restrict__ out_te,            // (B, L, OD)
    float* __restrict__ out_ts)            // (B, L)
{
    const int lane = threadIdx.x & 63;
    const int wave = threadIdx.x >> 6;
    const int blockbase = blockIdx.x * CHUNK;

    // Each wave: 2 independent 128-element rounds. No LDS, no barriers.
    #pragma unroll
    for (int r = 0; r < 2; ++r) {
        const int rbase = blockbase + r * 512 + wave * 128;

        // 2 coalesced ts loads (nontemporal: don't evict the table from L1).
        float tsv[2];
        #pragma unroll
        for (int u = 0; u < 2; ++u) {
            const int e   = rbase + u * 64 + lane;
            const int row = e >> 9;              // L == 512
            const int col = e & (L_DIM - 1);
            tsv[u] = __builtin_nontemporal_load(&timestamp[row * (L_DIM + 1) + col]);
        }

        // idx (bit-exact: IEEE div + floorf + clamp) and ts passthrough.
        int idxv[2];
        #pragma unroll
        for (int u = 0; u < 2; ++u) {
            float q = tsv[u] / 1000.0f;
            int idx = (int)floorf(q);
            idxv[u] = idx < 0 ? 0 : (idx > NT - 1 ? NT - 1 : idx);
            out_ts[rbase + u * 64 + lane] = tsv[u];
        }

        // 4 quarters: lane l stores the 16B unit (q*64 + l) of this round.
        // Element el = q*32 + (l>>1), half = l&1. Its idx lives in register
        // idxv[q>>1] of lane (q&1)*32 + (l>>1) -> intra-wave shfl.
        const int half = lane & 1;
        const int src  = lane >> 1;
        #pragma unroll
        for (int q = 0; q < 4; ++q) {
            const int sidx = __shfl(idxv[q >> 1], (q & 1) * 32 + src, 64);
            const float4n v = *reinterpret_cast<const float4n*>(
                &wt_g[swz(2 * sidx + half) * 4]);
            // float offset rbase*8 + q*256 + lane*4: consecutive lanes write
            // consecutive 16 B -> fully coalesced 1 KB/wave stores.
            *reinterpret_cast<float4n*>(
                out_te + (size_t)rbase * OD + (q * 64 + lane) * 4) = v;
        }
    }
}

extern "C" void kernel_launch(void* const* d_in, const int* in_sizes, int n_in,
                              void* d_out, int out_size, void* d_ws, size_t ws_size,
                              hipStream_t stream) {
    // Inputs (setup_inputs order): input (int32, unused), timestamp (f32),
    // W (f32, 8x1000), b (f32, 8).
    const float* timestamp = (const float*)d_in[1];
    const float* W         = (const float*)d_in[2];
    const float* bias      = (const float*)d_in[3];

    float* out = (float*)d_out;
    float* out_te = out;                                    // B*L*8 floats
    float* out_ts = out + (size_t)B_DIM * L_DIM * OD;       // B*L floats
    float* wt_g   = (float*)d_ws;                           // 32 KB table

    build_table<<<32, 256, 0, stream>>>(W, bias, wt_g);
    ste_kernel<<<NBLK, 256, 0, stream>>>(timestamp, wt_g, out_te, out_ts);
}

// Round 7
// 25.911 us; speedup vs baseline: 1.0370x; 1.0370x over previous
//
#include <hip/hip_runtime.h>

#define B_DIM 4096
#define L_DIM 512
#define NT 1000
#define OD 8
#define TOTAL (B_DIM * L_DIM)   // 2,097,152
#define CHUNK 2048               // elements per block
#define NBLK (TOTAL / CHUNK)     // 1024 = 4 blocks/CU x 256 CUs, one batch

typedef float float4n __attribute__((ext_vector_type(4)));

// Fused table: unit u = 2*idx + half (16 B), XOR-swizzled us = u ^ ((u>>3)&7)
// into 2048 units = 32 KB. Bank cluster (us%8) uniform for random idx.
__device__ __forceinline__ int swz(int u) { return u ^ ((u >> 3) & 7); }

__global__ __launch_bounds__(256) void ste_kernel(
    const float* __restrict__ timestamp,   // (B, L+1)
    const float* __restrict__ W,           // (OD, NT)
    const float* __restrict__ bias,        // (OD,)
    float* __restrict__ out_te,            // (B, L, OD)
    float* __restrict__ out_ts)            // (B, L)
{
    __shared__ float wt[2048 * 4];   // 32 KB swizzled fused table
    __shared__ int   sidx[CHUNK];    // 8 KB

    const int tid  = threadIdx.x;
    const int base = blockIdx.x * CHUNK;

    // (1) Issue the 8 independent coalesced ts HBM loads FIRST; everything in
    // (2) runs while they are in flight.
    float tsv[8];
    #pragma unroll
    for (int u = 0; u < 8; ++u) {
        const int e   = base + u * 256 + tid;
        const int row = e >> 9;             // L == 512
        const int col = e & (L_DIM - 1);
        tsv[u] = timestamp[row * (L_DIM + 1) + col];
    }

    // (2) Build the fused table in LDS from W (L2-resident after block 0).
    // Per j: 1000 coalesced reads across the block; ~32 independent loads per
    // thread total — overlaps the ts load latency.
    #pragma unroll
    for (int j = 0; j < OD; ++j) {
        const float bj = bias[j];
        #pragma unroll
        for (int r = tid; r < NT; r += 256) {
            const float val = W[j * NT + r] + bj;
            const int u = 2 * r + (j >> 2);
            wt[swz(u) * 4 + (j & 3)] = val;
        }
    }

    // (3) idx -> LDS; ts passthrough (plain coalesced dword stores).
    #pragma unroll
    for (int u = 0; u < 8; ++u) {
        float q = tsv[u] / 1000.0f;
        int idx = (int)floorf(q);
        idx = idx < 0 ? 0 : (idx > NT - 1 ? NT - 1 : idx);
        sidx[u * 256 + tid] = idx;
        out_ts[base + u * 256 + tid] = tsv[u];
    }
    __syncthreads();

    // (4) 16 independent gather->store chains per thread. g = u*256+tid ->
    // element g>>1, half g&1; consecutive lanes write consecutive 16B.
    #pragma unroll
    for (int u = 0; u < 16; ++u) {
        const int g    = u * 256 + tid;
        const int el   = g >> 1;
        const int half = g & 1;
        const int idx  = sidx[el];
        const float4n v =
            *reinterpret_cast<const float4n*>(&wt[swz(2 * idx + half) * 4]);
        *reinterpret_cast<float4n*>(
            out_te + (size_t)(base + el) * OD + half * 4) = v;
    }
}

extern "C" void kernel_launch(void* const* d_in, const int* in_sizes, int n_in,
                              void* d_out, int out_size, void* d_ws, size_t ws_size,
                              hipStream_t stream) {
    // Inputs (setup_inputs order): input (int32, unused), timestamp (f32),
    // W (f32, 8x1000), b (f32, 8).
    const float* timestamp = (const float*)d_in[1];
    const float* W         = (const float*)d_in[2];
    const float* bias      = (const float*)d_in[3];

    float* out = (float*)d_out;
    float* out_te = out;                                    // B*L*8 floats
    float* out_ts = out + (size_t)B_DIM * L_DIM * OD;       // B*L floats

    ste_kernel<<<NBLK, 256, 0, stream>>>(timestamp, W, bias, out_te, out_ts);
}

// Round 8
// 24.302 us; speedup vs baseline: 1.1057x; 1.0662x over previous
//
#include <hip/hip_runtime.h>

#define B_DIM 4096
#define L_DIM 512
#define NT 1000
#define OD 8
#define TOTAL (B_DIM * L_DIM)   // 2,097,152
#define CHUNK 2048               // elements per block (4 waves x 4 rounds x 128)
#define NBLK (TOTAL / CHUNK)     // 1024 blocks = 4 blocks/CU, one batch
#define ROUNDS 4

typedef float float4n __attribute__((ext_vector_type(4)));

// Fused table: unit u = 2*idx + half (16 B), XOR-swizzled us = u ^ ((u>>3)&7)
// into 2048 units = 32 KB. Bank cluster (us%8) uniform for random idx.
// Stored PRE-SWIZZLED in d_ws so the main kernel DMAs it linearly.
__device__ __forceinline__ int swz(int u) { return u ^ ((u >> 3) & 7); }

__global__ __launch_bounds__(256) void build_table(
    const float* __restrict__ W,     // (OD, NT)
    const float* __restrict__ bias,  // (OD,)
    float* __restrict__ wt_g)        // 2048*4 floats, swizzled layout
{
    const int k = blockIdx.x * 256 + threadIdx.x;   // 0..8191
    if (k < NT * OD) {
        const int r = k >> 3;   // time bucket
        const int j = k & 7;    // out dim
        const float val = W[j * NT + r] + bias[j];
        const int u = 2 * r + (j >> 2);
        wt_g[swz(u) * 4 + (j & 3)] = val;
    }
}

__global__ __launch_bounds__(256) void ste_kernel(
    const float* __restrict__ timestamp,   // (B, L+1)
    const float* __restrict__ wt_g,        // swizzled table in d_ws
    float* __restrict__ out_te,            // (B, L, OD)
    float* __restrict__ out_ts)            // (B, L)
{
    __shared__ float wt[2048 * 4];   // 32 KB swizzled fused table (only LDS)

    const int tid  = threadIdx.x;
    const int lane = tid & 63;
    const int wave = tid >> 6;
    const int wavebase = blockIdx.x * CHUNK + wave * (CHUNK / 4);

    // Round-0 ts loads issued FIRST (in flight during the table DMA).
    float tcur[2];
    #pragma unroll
    for (int u = 0; u < 2; ++u) {
        const int e   = wavebase + u * 64 + lane;
        const int row = e >> 9;              // L == 512
        const int col = e & (L_DIM - 1);
        tcur[u] = timestamp[row * (L_DIM + 1) + col];
    }

    // DMA the 32 KB table straight into LDS: 8 x (256 lanes x 16 B), linear.
    #pragma unroll
    for (int u = 0; u < 8; ++u) {
        const int off = (u * 256 + tid) * 4;
        __builtin_amdgcn_global_load_lds(
            (const __attribute__((address_space(1))) void*)(wt_g + off),
            (__attribute__((address_space(3))) void*)(wt + off),
            16, 0, 0);
    }
    __syncthreads();   // the ONLY barrier; drains DMA (round-0 loads too)

    // 4 autonomous rounds per wave, software-pipelined: round r+1's ts loads
    // are issued before round r's gather/store work, so HBM read latency
    // hides under stores and waves drift out of lockstep (steady mixed
    // HBM stream). No LDS for idx: intra-wave __shfl exchanges it.
    const int half = lane & 1;
    const int src  = lane >> 1;
    #pragma unroll
    for (int r = 0; r < ROUNDS; ++r) {
        const int rbase = wavebase + r * 128;

        float tnext[2];
        if (r + 1 < ROUNDS) {
            #pragma unroll
            for (int u = 0; u < 2; ++u) {
                const int e   = rbase + 128 + u * 64 + lane;
                const int row = e >> 9;
                const int col = e & (L_DIM - 1);
                tnext[u] = timestamp[row * (L_DIM + 1) + col];
            }
        }

        // idx (bit-exact: IEEE div + floorf + clamp) and ts passthrough.
        int idxv[2];
        #pragma unroll
        for (int u = 0; u < 2; ++u) {
            float q = tcur[u] / 1000.0f;
            int idx = (int)floorf(q);
            idxv[u] = idx < 0 ? 0 : (idx > NT - 1 ? NT - 1 : idx);
            __builtin_nontemporal_store(tcur[u], &out_ts[rbase + u * 64 + lane]);
        }

        // 4 quarters: lane l stores 16B unit (q*64 + l) of this round.
        // el = q*32 + (l>>1); its idx lives in reg q>>1 of lane (q&1)*32+(l>>1).
        #pragma unroll
        for (int q = 0; q < 4; ++q) {
            const int sidx = __shfl(idxv[q >> 1], (q & 1) * 32 + src, 64);
            const float4n v =
                *reinterpret_cast<const float4n*>(&wt[swz(2 * sidx + half) * 4]);
            __builtin_nontemporal_store(
                v, reinterpret_cast<float4n*>(
                       out_te + (size_t)rbase * OD + (q * 64 + lane) * 4));
        }

        if (r + 1 < ROUNDS) {
            tcur[0] = tnext[0];
            tcur[1] = tnext[1];
        }
    }
}

extern "C" void kernel_launch(void* const* d_in, const int* in_sizes, int n_in,
                              void* d_out, int out_size, void* d_ws, size_t ws_size,
                              hipStream_t stream) {
    // Inputs (setup_inputs order): input (int32, unused), timestamp (f32),
    // W (f32, 8x1000), b (f32, 8).
    const float* timestamp = (const float*)d_in[1];
    const float* W         = (const float*)d_in[2];
    const float* bias      = (const float*)d_in[3];

    float* out = (float*)d_out;
    float* out_te = out;                                    // B*L*8 floats
    float* out_ts = out + (size_t)B_DIM * L_DIM * OD;       // B*L floats
    float* wt_g   = (float*)d_ws;                           // 32 KB table

    build_table<<<32, 256, 0, stream>>>(W, bias, wt_g);
    ste_kernel<<<NBLK, 256, 0, stream>>>(timestamp, wt_g, out_te, out_ts);
}

// Round 9
// 22.290 us; speedup vs baseline: 1.2055x; 1.0903x over previous
//
#include <hip/hip_runtime.h>

#define B_DIM 4096
#define L_DIM 512
#define NT 1000
#define OD 8
#define TOTAL (B_DIM * L_DIM)   // 2,097,152
#define CHUNK 2048               // elements per block (4 waves x 4 rounds x 128)
#define NBLK (TOTAL / CHUNK)     // 1024 blocks = 4 blocks/CU, one batch
#define ROUNDS 4

typedef float float4n __attribute__((ext_vector_type(4)));

// Fused table: unit u = 2*idx + half (16 B), XOR-swizzled us = u ^ ((u>>3)&7)
// into 2048 units = 32 KB. Bank cluster (us%8) uniform for random idx.
__device__ __forceinline__ int swz(int u) { return u ^ ((u >> 3) & 7); }

__global__ __launch_bounds__(256) void ste_kernel(
    const float* __restrict__ timestamp,   // (B, L+1)
    const float* __restrict__ W,           // (OD, NT)
    const float* __restrict__ bias,        // (OD,)
    float* __restrict__ out_te,            // (B, L, OD)
    float* __restrict__ out_ts)            // (B, L)
{
    __shared__ float wt[2048 * 4];   // 32 KB swizzled fused table (only LDS)

    const int tid  = threadIdx.x;
    const int lane = tid & 63;
    const int wave = tid >> 6;
    const int wavebase = blockIdx.x * CHUNK + wave * (CHUNK / 4);

    // Round-0 ts loads issued FIRST (in flight during the table build).
    float tcur[2];
    #pragma unroll
    for (int u = 0; u < 2; ++u) {
        const int e   = wavebase + u * 64 + lane;
        const int row = e >> 9;              // L == 512
        const int col = e & (L_DIM - 1);
        tcur[u] = timestamp[row * (L_DIM + 1) + col];
    }

    // In-block table build: 32 independent W loads/thread (L2-broadcast
    // across blocks) + bias add + swizzled LDS writes. Overlaps the ts loads.
    #pragma unroll
    for (int j = 0; j < OD; ++j) {
        const float bj = bias[j];
        #pragma unroll
        for (int i = 0; i < 4; ++i) {
            const int r = i * 256 + tid;
            if (r < NT) {
                const float val = W[j * NT + r] + bj;
                const int u = 2 * r + (j >> 2);
                wt[swz(u) * 4 + (j & 3)] = val;
            }
        }
    }
    __syncthreads();   // the ONLY barrier

    // 4 autonomous rounds per wave, software-pipelined: round r+1's ts loads
    // are issued before round r's gather/store work. Idx exchange via
    // intra-wave __shfl (no LDS, no extra barriers).
    const int half = lane & 1;
    const int src  = lane >> 1;
    #pragma unroll
    for (int r = 0; r < ROUNDS; ++r) {
        const int rbase = wavebase + r * 128;

        float tnext[2];
        if (r + 1 < ROUNDS) {
            #pragma unroll
            for (int u = 0; u < 2; ++u) {
                const int e   = rbase + 128 + u * 64 + lane;
                const int row = e >> 9;
                const int col = e & (L_DIM - 1);
                tnext[u] = timestamp[row * (L_DIM + 1) + col];
            }
        }

        // idx (bit-exact: IEEE div + floorf + clamp) and ts passthrough.
        int idxv[2];
        #pragma unroll
        for (int u = 0; u < 2; ++u) {
            float q = tcur[u] / 1000.0f;
            int idx = (int)floorf(q);
            idxv[u] = idx < 0 ? 0 : (idx > NT - 1 ? NT - 1 : idx);
            __builtin_nontemporal_store(tcur[u], &out_ts[rbase + u * 64 + lane]);
        }

        // 4 quarters: lane l stores 16B unit (q*64 + l) of this round.
        // el = q*32 + (l>>1); its idx lives in reg q>>1 of lane (q&1)*32+(l>>1).
        #pragma unroll
        for (int q = 0; q < 4; ++q) {
            const int sidx = __shfl(idxv[q >> 1], (q & 1) * 32 + src, 64);
            const float4n v =
                *reinterpret_cast<const float4n*>(&wt[swz(2 * sidx + half) * 4]);
            __builtin_nontemporal_store(
                v, reinterpret_cast<float4n*>(
                       out_te + (size_t)rbase * OD + (q * 64 + lane) * 4));
        }

        if (r + 1 < ROUNDS) {
            tcur[0] = tnext[0];
            tcur[1] = tnext[1];
        }
    }
}

extern "C" void kernel_launch(void* const* d_in, const int* in_sizes, int n_in,
                              void* d_out, int out_size, void* d_ws, size_t ws_size,
                              hipStream_t stream) {
    // Inputs (setup_inputs order): input (int32, unused), timestamp (f32),
    // W (f32, 8x1000), b (f32, 8).
    const float* timestamp = (const float*)d_in[1];
    const float* W         = (const float*)d_in[2];
    const float* bias      = (const float*)d_in[3];

    float* out = (float*)d_out;
    float* out_te = out;                                    // B*L*8 floats
    float* out_ts = out + (size_t)B_DIM * L_DIM * OD;       // B*L floats

    ste_kernel<<<NBLK, 256, 0, stream>>>(timestamp, W, bias, out_te, out_ts);
}